// Round 6
// baseline (441.835 us; speedup 1.0000x reference)
//
#include <hip/hip_runtime.h>
#include <hip/hip_bf16.h>
#include <math.h>

#define GENES 1000

typedef __attribute__((ext_vector_type(8))) _Float16 half8;
typedef __attribute__((ext_vector_type(4))) float f32x4;
typedef __attribute__((ext_vector_type(4))) unsigned int uint4v;

// ---------------- CSR build ----------------

__global__ void k_deg(const int* __restrict__ ei, int* __restrict__ deg, int E) {
  int e = blockIdx.x * blockDim.x + threadIdx.x;
  if (e < E) atomicAdd(&deg[ei[E + e]], 1);
}

__global__ void k_scan1(const int* __restrict__ deg, int* __restrict__ ptr,
                        int* __restrict__ bsum, int n) {
  __shared__ int ws[4];
  int t = threadIdx.x, b = blockIdx.x;
  int i = b * 256 + t;
  int lane = t & 63, w = t >> 6;
  int x = (i < n) ? deg[i] : 0;
  #pragma unroll
  for (int d = 1; d < 64; d <<= 1) {
    int y = __shfl_up(x, d);
    if (lane >= d) x += y;
  }
  if (lane == 63) ws[w] = x;
  __syncthreads();
  if (t == 0) {
    int s = 0;
    #pragma unroll
    for (int k = 0; k < 4; ++k) { s += ws[k]; ws[k] = s; }
  }
  __syncthreads();
  int incl = x + (w ? ws[w - 1] : 0);
  if (i < n) ptr[i + 1] = incl;
  if (t == 255) bsum[b] = incl;
  if (i == 0) ptr[0] = 0;
}

__global__ void k_scan2(int* __restrict__ bsum, int nb) {
  __shared__ int ws[4];
  int t = threadIdx.x;
  int lane = t & 63, w = t >> 6;
  int v = (t < nb) ? bsum[t] : 0;
  int x = v;
  #pragma unroll
  for (int d = 1; d < 64; d <<= 1) {
    int y = __shfl_up(x, d);
    if (lane >= d) x += y;
  }
  if (lane == 63) ws[w] = x;
  __syncthreads();
  if (t == 0) {
    int s = 0;
    #pragma unroll
    for (int k = 0; k < 4; ++k) { s += ws[k]; ws[k] = s; }
  }
  __syncthreads();
  int incl = x + (w ? ws[w - 1] : 0);
  if (t < nb) bsum[t] = incl - v;
}

__global__ void k_scan3(int* __restrict__ ptr, const int* __restrict__ bsum, int n) {
  int i = blockIdx.x * 256 + threadIdx.x;
  if (i < n) ptr[i + 1] += bsum[blockIdx.x];
}

__global__ void k_scatter(const int* __restrict__ ei, const int* __restrict__ ptr,
                          int* __restrict__ cur, int* __restrict__ srcs, int E) {
  int e = blockIdx.x * blockDim.x + threadIdx.x;
  if (e >= E) return;
  int d = ei[E + e];
  int pos = ptr[d] + atomicAdd(&cur[d], 1);
  srcs[pos] = ei[e];
}

// ---------------- W pack (all 3 layers, one launch) ----------------
// Region layout per layer: element e = s*4096 + col*32 + kk  (s = k-step of 32)
// -> fragment for lane l, tile nt at byte 2e: [s][col][kk] fp16.
// Sizes: W0 -> 32 ksteps (K padded 1024), W1 -> 4, W2 -> 4 (cols padded to 128).

__global__ void k_wpackall(const float* __restrict__ W0, const float* __restrict__ W1,
                           const float* __restrict__ W2, unsigned short* __restrict__ P,
                           int K0) {
  int t = blockIdx.x * blockDim.x + threadIdx.x;  // 163840 total
  if (t >= 163840) return;
  const float* W; int K, N, e;
  if (t < 131072)      { W = W0; K = K0;  N = 128; e = t; }
  else if (t < 147456) { W = W1; K = 128; N = 128; e = t - 131072; }
  else                 { W = W2; K = 128; N = 16;  e = t - 147456; }
  int s = e >> 12, rem = e & 4095, col = rem >> 5, kk = rem & 31;
  int k = s * 32 + kk;
  float v = (k < K && col < N) ? W[(long)k * N + col] : 0.f;
  _Float16 h = (_Float16)v;
  P[t] = __builtin_bit_cast(unsigned short, h);
}

// ---------------- MFMA fp16 GEMM: no LDS, no barriers, B streamed from L2 -------
// 256 threads = 4 waves; wave w owns rows blk*64 + w*16 + r15, all NW*16 cols.
// Depth-1 register double-buffer pipeline; waves free-run (TLP+MLP latency hiding).
// Fused epilogue: out (fp16 or fp32) + attention coefficients als/ald.

template<int HH, int NW, bool AF16, bool OF16>
__global__ __launch_bounds__(256, 3) void k_mgemm4(
    const void* __restrict__ Ap, const unsigned short* __restrict__ Bpk,
    void* __restrict__ outp, float* __restrict__ als, float* __restrict__ ald,
    const float* __restrict__ avs, const float* __restrict__ avd,
    int M, int K, int nst, int ldc) {
  int t = threadIdx.x, lane = t & 63, w = t >> 6;
  int r15 = lane & 15, q = lane >> 4;
  long row = (long)blockIdx.x * 64 + w * 16 + r15;
  bool rok = row < M;
  const float* a32 = (const float*)Ap + row * (long)K;
  const unsigned short* a16 = (const unsigned short*)Ap + row * (long)K;
  // per-lane B base: byte = r15*64 + q*16 (+ s*8192 + nt*1024)
  const char* bptr = (const char*)Bpk + r15 * 64 + q * 16;

  f32x4 acc[NW];
  #pragma unroll
  for (int nt = 0; nt < NW; ++nt) acc[nt] = (f32x4){0.f, 0.f, 0.f, 0.f};

  uint4v b0[NW], b1[NW];
  float4 lo0, hi0, lo1, hi1;
  uint4v h0, h1;
  const uint4v z4 = (uint4v){0u, 0u, 0u, 0u};

  auto loadB = [&](int s, uint4v* bb) {
    const char* p = bptr + s * 8192;
    #pragma unroll
    for (int nt = 0; nt < NW; ++nt)
      bb[nt] = *(const uint4v*)(p + nt * 1024);
  };
  auto loadA32 = [&](int s, float4& lo, float4& hi) {
    int k0 = s * 32 + q * 8;
    if (rok && k0 + 8 <= K) {
      lo = *(const float4*)(a32 + k0);
      hi = *(const float4*)(a32 + k0 + 4);
    } else {
      lo = make_float4(0.f, 0.f, 0.f, 0.f);
      hi = make_float4(0.f, 0.f, 0.f, 0.f);
    }
  };
  auto loadA16 = [&](int s, uint4v& v) {
    int k0 = s * 32 + q * 8;
    v = (rok && k0 + 8 <= K) ? *(const uint4v*)(a16 + k0) : z4;
  };
  auto mkfrag32 = [&](const float4& lo, const float4& hi) -> half8 {
    uint4v au;
    au[0] = __builtin_bit_cast(unsigned int, __builtin_amdgcn_cvt_pkrtz(lo.x, lo.y));
    au[1] = __builtin_bit_cast(unsigned int, __builtin_amdgcn_cvt_pkrtz(lo.z, lo.w));
    au[2] = __builtin_bit_cast(unsigned int, __builtin_amdgcn_cvt_pkrtz(hi.x, hi.y));
    au[3] = __builtin_bit_cast(unsigned int, __builtin_amdgcn_cvt_pkrtz(hi.z, hi.w));
    return __builtin_bit_cast(half8, au);
  };
  auto compute = [&](half8 af, uint4v* bb) {
    #pragma unroll
    for (int nt = 0; nt < NW; ++nt)
      acc[nt] = __builtin_amdgcn_mfma_f32_16x16x32_f16(
          af, __builtin_bit_cast(half8, bb[nt]), acc[nt], 0, 0, 0);
  };

  loadB(0, b0);
  if constexpr (AF16) loadA16(0, h0); else loadA32(0, lo0, hi0);

  for (int s = 0; s < nst; s += 2) {
    bool n1 = s + 1 < nst, n2 = s + 2 < nst;
    if (n1) {
      loadB(s + 1, b1);
      if constexpr (AF16) loadA16(s + 1, h1); else loadA32(s + 1, lo1, hi1);
    }
    {
      half8 af;
      if constexpr (AF16) af = __builtin_bit_cast(half8, h0);
      else af = mkfrag32(lo0, hi0);
      compute(af, b0);
    }
    if (n2) {
      loadB(s + 2, b0);
      if constexpr (AF16) loadA16(s + 2, h0); else loadA32(s + 2, lo0, hi0);
    }
    if (n1) {
      half8 af;
      if constexpr (AF16) af = __builtin_bit_cast(half8, h1);
      else af = mkfrag32(lo1, hi1);
      compute(af, b1);
    }
  }

  // ---- epilogue: C/D layout col=lane&15, row=(lane>>4)*4+i ----
  long rbase = (long)blockIdx.x * 64 + w * 16 + q * 4;
  if constexpr (OF16) {
    unsigned short* o16 = (unsigned short*)outp;
    #pragma unroll
    for (int i = 0; i < 4; ++i) {
      long r = rbase + i;
      if (r < M) {
        #pragma unroll
        for (int nt = 0; nt < NW; ++nt) {
          _Float16 hv = (_Float16)acc[nt][i];
          o16[r * ldc + nt * 16 + r15] = __builtin_bit_cast(unsigned short, hv);
        }
      }
    }
  } else {
    float* o32 = (float*)outp;
    #pragma unroll
    for (int i = 0; i < 4; ++i) {
      long r = rbase + i;
      if (r < M) {
        #pragma unroll
        for (int nt = 0; nt < NW; ++nt)
          o32[r * ldc + nt * 16 + r15] = acc[nt][i];
      }
    }
  }
  // fused attention coefficients
  #pragma unroll
  for (int h = 0; h < HH; ++h) {
    float cs = avs[h * 16 + r15];
    float cd = avd[h * 16 + r15];
    #pragma unroll
    for (int i = 0; i < 4; ++i) {
      float s1 = acc[h][i] * cs;
      float s2 = acc[h][i] * cd;
      #pragma unroll
      for (int d = 1; d < 16; d <<= 1) {
        s1 += __shfl_xor(s1, d);
        s2 += __shfl_xor(s2, d);
      }
      if (r15 == 0) {
        long r = rbase + i;
        if (r < M) { als[r * HH + h] = s1; ald[r * HH + h] = s2; }
      }
    }
  }
}

// ---------------- per-dst aggregation, H=8, C=16, fp16 h in / fp16 out, ELU ----------------

__global__ void k_agg128h(const unsigned short* __restrict__ h,
                          const float* __restrict__ als, const float* __restrict__ ald,
                          const int* __restrict__ ptr, const int* __restrict__ srcs,
                          const float* __restrict__ bias,
                          unsigned short* __restrict__ out, int n) {
  int wid = (int)(((long)blockIdx.x * blockDim.x + threadIdx.x) >> 6);
  if (wid >= n) return;
  int lane = threadIdx.x & 63;
  int p0 = ptr[wid], deg = ptr[wid + 1] - p0;
  int hA = lane & 7;
  float aldA = ald[wid * 8 + hA];
  float mx = -1e30f;
  for (int j = (lane >> 3); j < deg; j += 8) {
    float l = als[srcs[p0 + j] * 8 + hA] + aldA;
    l = l > 0.f ? l : 0.2f * l;
    mx = fmaxf(mx, l);
  }
  #pragma unroll
  for (int d = 8; d < 64; d <<= 1) mx = fmaxf(mx, __shfl_xor(mx, d));
  int hB = lane >> 3;
  float m = __shfl(mx, hB);
  float aldB = ald[wid * 8 + hB];
  int c0 = 2 * lane;
  float acc0 = 0.f, acc1 = 0.f, dsum = 0.f;
  for (int j = 0; j < deg; ++j) {
    int s = srcs[p0 + j];
    float l = als[s * 8 + hB] + aldB;
    l = l > 0.f ? l : 0.2f * l;
    float e = __expf(l - m);
    dsum += e;
    unsigned int hv = *(const unsigned int*)(h + (long)s * 128 + c0);
    float f0 = (float)__builtin_bit_cast(_Float16, (unsigned short)(hv & 0xffffu));
    float f1 = (float)__builtin_bit_cast(_Float16, (unsigned short)(hv >> 16));
    acc0 += e * f0;
    acc1 += e * f1;
  }
  float inv = 1.f / (dsum + 1e-16f);
  float o0 = acc0 * inv + bias[c0];
  float o1 = acc1 * inv + bias[c0 + 1];
  o0 = o0 > 0.f ? o0 : (__expf(o0) - 1.f);
  o1 = o1 > 0.f ? o1 : (__expf(o1) - 1.f);
  unsigned int po = __builtin_bit_cast(unsigned int, __builtin_amdgcn_cvt_pkrtz(o0, o1));
  *(unsigned int*)(out + (long)wid * 128 + c0) = po;
}

// ---------------- per-dst aggregation, H=1, C=16, fp32 ----------------

__global__ void k_agg16(const float* __restrict__ h, const float* __restrict__ als,
                        const float* __restrict__ ald, const int* __restrict__ ptr,
                        const int* __restrict__ srcs, const float* __restrict__ bias,
                        float* __restrict__ out, int n, int lda) {
  int wid = (int)(((long)blockIdx.x * blockDim.x + threadIdx.x) >> 6);
  if (wid >= n) return;
  int lane = threadIdx.x & 63;
  int p0 = ptr[wid], deg = ptr[wid + 1] - p0;
  float aldv = ald[wid];
  float mx = -1e30f;
  for (int j = lane; j < deg; j += 64) {
    float l = als[srcs[p0 + j]] + aldv;
    l = l > 0.f ? l : 0.2f * l;
    mx = fmaxf(mx, l);
  }
  #pragma unroll
  for (int d = 1; d < 64; d <<= 1) mx = fmaxf(mx, __shfl_xor(mx, d));
  int g = lane >> 4, c = lane & 15;
  float acc = 0.f, dsum = 0.f;
  for (int j = g; j < deg; j += 4) {
    int s = srcs[p0 + j];
    float l = als[s] + aldv;
    l = l > 0.f ? l : 0.2f * l;
    float e = __expf(l - mx);
    dsum += e;
    acc += e * h[(long)s * lda + c];
  }
  #pragma unroll
  for (int d = 16; d < 64; d <<= 1) {
    acc += __shfl_xor(acc, d);
    dsum += __shfl_xor(dsum, d);
  }
  if (lane < 16)
    out[(long)wid * 16 + lane] = acc / (dsum + 1e-16f) + bias[lane];
}

// ---------------- launch ----------------

extern "C" void kernel_launch(void* const* d_in, const int* in_sizes, int n_in,
                              void* d_out, int out_size, void* d_ws, size_t ws_size,
                              hipStream_t stream) {
  const float* x  = (const float*)d_in[0];
  const int*   ei = (const int*)d_in[1];
  const float* W0 = (const float*)d_in[2];
  const float* as0= (const float*)d_in[3];
  const float* ad0= (const float*)d_in[4];
  const float* b0 = (const float*)d_in[5];
  const float* W1 = (const float*)d_in[6];
  const float* as1= (const float*)d_in[7];
  const float* ad1= (const float*)d_in[8];
  const float* b1 = (const float*)d_in[9];
  const float* W2 = (const float*)d_in[10];
  const float* as2= (const float*)d_in[11];
  const float* ad2= (const float*)d_in[12];
  const float* b2 = (const float*)d_in[13];
  float* out = (float*)d_out;

  int E = in_sizes[1] / 2;
  int n = in_sizes[0] / GENES;

  char* ws = (char*)d_ws;
  size_t off = 0;
  auto alloc = [&](size_t bytes) {
    void* p = ws + off;
    off = (off + bytes + 255) & ~(size_t)255;
    return p;
  };
  int* ptr   = (int*)alloc((size_t)(n + 1) * sizeof(int));
  int* cur   = (int*)alloc((size_t)n * sizeof(int));
  int* bsum  = (int*)alloc(512 * sizeof(int));
  int* srcs  = (int*)alloc((size_t)E * sizeof(int));
  unsigned short* Ah = (unsigned short*)alloc((size_t)n * 128 * sizeof(unsigned short));
  unsigned short* Bh = (unsigned short*)alloc((size_t)n * 128 * sizeof(unsigned short));
  float* A2  = (float*)alloc((size_t)n * 16 * sizeof(float));
  float* als = (float*)alloc((size_t)n * 8 * sizeof(float));
  float* ald = (float*)alloc((size_t)n * 8 * sizeof(float));
  unsigned short* P = (unsigned short*)alloc((size_t)163840 * sizeof(unsigned short));
  unsigned short* P0 = P;
  unsigned short* P1 = P + 131072;
  unsigned short* P2 = P + 147456;

  int eb = (E + 255) / 256;
  int nb = (n + 255) / 256;
  hipMemsetAsync(cur, 0, (size_t)n * sizeof(int), stream);
  k_deg<<<eb, 256, 0, stream>>>(ei, cur, E);
  k_scan1<<<nb, 256, 0, stream>>>(cur, ptr, bsum, n);
  k_scan2<<<1, 256, 0, stream>>>(bsum, nb);
  k_scan3<<<nb, 256, 0, stream>>>(ptr, bsum, n);
  hipMemsetAsync(cur, 0, (size_t)n * sizeof(int), stream);
  k_scatter<<<eb, 256, 0, stream>>>(ei, ptr, cur, srcs, E);
  k_wpackall<<<640, 256, 0, stream>>>(W0, W1, W2, P, GENES);

  int mgb  = (n + 63) / 64;
  int aggb = (int)(((long)n * 64 + 255) / 256);

  // layer 0: x @ W0 -> Ah fp16 (+als/ald), aggregate -> Bh fp16 (ELU)
  k_mgemm4<8, 8, false, true><<<mgb, 256, 0, stream>>>(
      x, P0, Ah, als, ald, as0, ad0, n, GENES, 32, 128);
  k_agg128h<<<aggb, 256, 0, stream>>>(Ah, als, ald, ptr, srcs, b0, Bh, n);

  // layer 1: Bh @ W1 -> Ah fp16 (+als/ald), aggregate -> Bh fp16 (ELU)
  k_mgemm4<8, 8, true, true><<<mgb, 256, 0, stream>>>(
      Bh, P1, Ah, als, ald, as1, ad1, n, 128, 4, 128);
  k_agg128h<<<aggb, 256, 0, stream>>>(Ah, als, ald, ptr, srcs, b1, Bh, n);

  // layer 2: Bh @ W2 (padded) -> A2 fp32 [n][16] (+als/ald H=1), aggregate -> out
  k_mgemm4<1, 1, true, false><<<mgb, 256, 0, stream>>>(
      Bh, P2, A2, als, ald, as2, ad2, n, 128, 4, 16);
  k_agg16<<<aggb, 256, 0, stream>>>(A2, als, ald, ptr, srcs, b2, out, n, 16);
}

// Round 7
// 441.579 us; speedup vs baseline: 1.0006x; 1.0006x over previous
//
#include <hip/hip_runtime.h>
#include <hip/hip_bf16.h>
#include <math.h>

#define GENES 1000

typedef __attribute__((ext_vector_type(8))) _Float16 half8;
typedef __attribute__((ext_vector_type(4))) float f32x4;
typedef __attribute__((ext_vector_type(4))) unsigned int uint4v;

// ---------------- CSR build ----------------

__global__ void k_deg(const int* __restrict__ ei, int* __restrict__ deg, int E) {
  int e = blockIdx.x * blockDim.x + threadIdx.x;
  if (e < E) atomicAdd(&deg[ei[E + e]], 1);
}

__global__ void k_scan1(const int* __restrict__ deg, int* __restrict__ ptr,
                        int* __restrict__ bsum, int n) {
  __shared__ int ws[4];
  int t = threadIdx.x, b = blockIdx.x;
  int i = b * 256 + t;
  int lane = t & 63, w = t >> 6;
  int x = (i < n) ? deg[i] : 0;
  #pragma unroll
  for (int d = 1; d < 64; d <<= 1) {
    int y = __shfl_up(x, d);
    if (lane >= d) x += y;
  }
  if (lane == 63) ws[w] = x;
  __syncthreads();
  if (t == 0) {
    int s = 0;
    #pragma unroll
    for (int k = 0; k < 4; ++k) { s += ws[k]; ws[k] = s; }
  }
  __syncthreads();
  int incl = x + (w ? ws[w - 1] : 0);
  if (i < n) ptr[i + 1] = incl;
  if (t == 255) bsum[b] = incl;
  if (i == 0) ptr[0] = 0;
}

__global__ void k_scan2(int* __restrict__ bsum, int nb) {
  __shared__ int ws[4];
  int t = threadIdx.x;
  int lane = t & 63, w = t >> 6;
  int v = (t < nb) ? bsum[t] : 0;
  int x = v;
  #pragma unroll
  for (int d = 1; d < 64; d <<= 1) {
    int y = __shfl_up(x, d);
    if (lane >= d) x += y;
  }
  if (lane == 63) ws[w] = x;
  __syncthreads();
  if (t == 0) {
    int s = 0;
    #pragma unroll
    for (int k = 0; k < 4; ++k) { s += ws[k]; ws[k] = s; }
  }
  __syncthreads();
  int incl = x + (w ? ws[w - 1] : 0);
  if (t < nb) bsum[t] = incl - v;
}

__global__ void k_scan3(int* __restrict__ ptr, const int* __restrict__ bsum, int n) {
  int i = blockIdx.x * 256 + threadIdx.x;
  if (i < n) ptr[i + 1] += bsum[blockIdx.x];
}

__global__ void k_scatter(const int* __restrict__ ei, const int* __restrict__ ptr,
                          int* __restrict__ cur, int* __restrict__ srcs, int E) {
  int e = blockIdx.x * blockDim.x + threadIdx.x;
  if (e >= E) return;
  int d = ei[E + e];
  int pos = ptr[d] + atomicAdd(&cur[d], 1);
  srcs[pos] = ei[e];
}

// ---------------- W pack (all 3 layers, one launch) ----------------
// Region layout per layer: element e = s*4096 + col*32 + kk  (s = k-step of 32)
// -> fragment for lane l, tile nt at byte 2e: [s][col][kk] fp16.
// Sizes: W0 -> 32 ksteps (K padded 1024), W1 -> 4, W2 -> 4 (cols padded to 128).

__global__ void k_wpackall(const float* __restrict__ W0, const float* __restrict__ W1,
                           const float* __restrict__ W2, unsigned short* __restrict__ P,
                           int K0) {
  int t = blockIdx.x * blockDim.x + threadIdx.x;  // 163840 total
  if (t >= 163840) return;
  const float* W; int K, N, e;
  if (t < 131072)      { W = W0; K = K0;  N = 128; e = t; }
  else if (t < 147456) { W = W1; K = 128; N = 128; e = t - 131072; }
  else                 { W = W2; K = 128; N = 16;  e = t - 147456; }
  int s = e >> 12, rem = e & 4095, col = rem >> 5, kk = rem & 31;
  int k = s * 32 + kk;
  float v = (k < K && col < N) ? W[(long)k * N + col] : 0.f;
  _Float16 h = (_Float16)v;
  P[t] = __builtin_bit_cast(unsigned short, h);
}

// ---------------- MFMA fp16 GEMM: no LDS, no barriers, B streamed from L2 -------
// 256 threads = 4 waves; wave w owns rows blk*64 + w*16 + r15, all NW*16 cols.
// Depth-1 register double-buffer pipeline; waves free-run (TLP+MLP latency hiding).
// Fused epilogue: out (fp16 or fp32) + attention coefficients als/ald.

template<int HH, int NW, bool AF16, bool OF16>
__global__ __launch_bounds__(256, 3) void k_mgemm4(
    const void* __restrict__ Ap, const unsigned short* __restrict__ Bpk,
    void* __restrict__ outp, float* __restrict__ als, float* __restrict__ ald,
    const float* __restrict__ avs, const float* __restrict__ avd,
    int M, int K, int nst, int ldc) {
  int t = threadIdx.x, lane = t & 63, w = t >> 6;
  int r15 = lane & 15, q = lane >> 4;
  long row = (long)blockIdx.x * 64 + w * 16 + r15;
  bool rok = row < M;
  const float* a32 = (const float*)Ap + row * (long)K;
  const unsigned short* a16 = (const unsigned short*)Ap + row * (long)K;
  // per-lane B base: byte = r15*64 + q*16 (+ s*8192 + nt*1024)
  const char* bptr = (const char*)Bpk + r15 * 64 + q * 16;

  f32x4 acc[NW];
  #pragma unroll
  for (int nt = 0; nt < NW; ++nt) acc[nt] = (f32x4){0.f, 0.f, 0.f, 0.f};

  uint4v b0[NW], b1[NW];
  float4 lo0, hi0, lo1, hi1;
  uint4v h0, h1;
  const uint4v z4 = (uint4v){0u, 0u, 0u, 0u};

  auto loadB = [&](int s, uint4v* bb) {
    const char* p = bptr + s * 8192;
    #pragma unroll
    for (int nt = 0; nt < NW; ++nt)
      bb[nt] = *(const uint4v*)(p + nt * 1024);
  };
  auto loadA32 = [&](int s, float4& lo, float4& hi) {
    int k0 = s * 32 + q * 8;
    if (rok && k0 + 8 <= K) {
      lo = *(const float4*)(a32 + k0);
      hi = *(const float4*)(a32 + k0 + 4);
    } else {
      lo = make_float4(0.f, 0.f, 0.f, 0.f);
      hi = make_float4(0.f, 0.f, 0.f, 0.f);
    }
  };
  auto loadA16 = [&](int s, uint4v& v) {
    int k0 = s * 32 + q * 8;
    v = (rok && k0 + 8 <= K) ? *(const uint4v*)(a16 + k0) : z4;
  };
  auto mkfrag32 = [&](const float4& lo, const float4& hi) -> half8 {
    uint4v au;
    au[0] = __builtin_bit_cast(unsigned int, __builtin_amdgcn_cvt_pkrtz(lo.x, lo.y));
    au[1] = __builtin_bit_cast(unsigned int, __builtin_amdgcn_cvt_pkrtz(lo.z, lo.w));
    au[2] = __builtin_bit_cast(unsigned int, __builtin_amdgcn_cvt_pkrtz(hi.x, hi.y));
    au[3] = __builtin_bit_cast(unsigned int, __builtin_amdgcn_cvt_pkrtz(hi.z, hi.w));
    return __builtin_bit_cast(half8, au);
  };
  auto compute = [&](half8 af, uint4v* bb) {
    #pragma unroll
    for (int nt = 0; nt < NW; ++nt)
      acc[nt] = __builtin_amdgcn_mfma_f32_16x16x32_f16(
          af, __builtin_bit_cast(half8, bb[nt]), acc[nt], 0, 0, 0);
  };

  loadB(0, b0);
  if constexpr (AF16) loadA16(0, h0); else loadA32(0, lo0, hi0);

  for (int s = 0; s < nst; s += 2) {
    bool n1 = s + 1 < nst, n2 = s + 2 < nst;
    if (n1) {
      loadB(s + 1, b1);
      if constexpr (AF16) loadA16(s + 1, h1); else loadA32(s + 1, lo1, hi1);
    }
    {
      half8 af;
      if constexpr (AF16) af = __builtin_bit_cast(half8, h0);
      else af = mkfrag32(lo0, hi0);
      compute(af, b0);
    }
    if (n2) {
      loadB(s + 2, b0);
      if constexpr (AF16) loadA16(s + 2, h0); else loadA32(s + 2, lo0, hi0);
    }
    if (n1) {
      half8 af;
      if constexpr (AF16) af = __builtin_bit_cast(half8, h1);
      else af = mkfrag32(lo1, hi1);
      compute(af, b1);
    }
  }

  // ---- epilogue: C/D layout col=lane&15, row=(lane>>4)*4+i ----
  long rbase = (long)blockIdx.x * 64 + w * 16 + q * 4;
  if constexpr (OF16) {
    unsigned short* o16 = (unsigned short*)outp;
    #pragma unroll
    for (int i = 0; i < 4; ++i) {
      long r = rbase + i;
      if (r < M) {
        #pragma unroll
        for (int nt = 0; nt < NW; ++nt) {
          _Float16 hv = (_Float16)acc[nt][i];
          o16[r * ldc + nt * 16 + r15] = __builtin_bit_cast(unsigned short, hv);
        }
      }
    }
  } else {
    float* o32 = (float*)outp;
    #pragma unroll
    for (int i = 0; i < 4; ++i) {
      long r = rbase + i;
      if (r < M) {
        #pragma unroll
        for (int nt = 0; nt < NW; ++nt)
          o32[r * ldc + nt * 16 + r15] = acc[nt][i];
      }
    }
  }
  // fused attention coefficients
  #pragma unroll
  for (int h = 0; h < HH; ++h) {
    float cs = avs[h * 16 + r15];
    float cd = avd[h * 16 + r15];
    #pragma unroll
    for (int i = 0; i < 4; ++i) {
      float s1 = acc[h][i] * cs;
      float s2 = acc[h][i] * cd;
      #pragma unroll
      for (int d = 1; d < 16; d <<= 1) {
        s1 += __shfl_xor(s1, d);
        s2 += __shfl_xor(s2, d);
      }
      if (r15 == 0) {
        long r = rbase + i;
        if (r < M) { als[r * HH + h] = s1; ald[r * HH + h] = s2; }
      }
    }
  }
}

// ---------------- per-dst aggregation, H=8, C=16, fp16 h in / fp16 out, ELU ----------------

__global__ void k_agg128h(const unsigned short* __restrict__ h,
                          const float* __restrict__ als, const float* __restrict__ ald,
                          const int* __restrict__ ptr, const int* __restrict__ srcs,
                          const float* __restrict__ bias,
                          unsigned short* __restrict__ out, int n) {
  int wid = (int)(((long)blockIdx.x * blockDim.x + threadIdx.x) >> 6);
  if (wid >= n) return;
  int lane = threadIdx.x & 63;
  int p0 = ptr[wid], deg = ptr[wid + 1] - p0;
  int hA = lane & 7;
  float aldA = ald[wid * 8 + hA];
  float mx = -1e30f;
  for (int j = (lane >> 3); j < deg; j += 8) {
    float l = als[srcs[p0 + j] * 8 + hA] + aldA;
    l = l > 0.f ? l : 0.2f * l;
    mx = fmaxf(mx, l);
  }
  #pragma unroll
  for (int d = 8; d < 64; d <<= 1) mx = fmaxf(mx, __shfl_xor(mx, d));
  int hB = lane >> 3;
  float m = __shfl(mx, hB);
  float aldB = ald[wid * 8 + hB];
  int c0 = 2 * lane;
  float acc0 = 0.f, acc1 = 0.f, dsum = 0.f;
  for (int j = 0; j < deg; ++j) {
    int s = srcs[p0 + j];
    float l = als[s * 8 + hB] + aldB;
    l = l > 0.f ? l : 0.2f * l;
    float e = __expf(l - m);
    dsum += e;
    unsigned int hv = *(const unsigned int*)(h + (long)s * 128 + c0);
    float f0 = (float)__builtin_bit_cast(_Float16, (unsigned short)(hv & 0xffffu));
    float f1 = (float)__builtin_bit_cast(_Float16, (unsigned short)(hv >> 16));
    acc0 += e * f0;
    acc1 += e * f1;
  }
  float inv = 1.f / (dsum + 1e-16f);
  float o0 = acc0 * inv + bias[c0];
  float o1 = acc1 * inv + bias[c0 + 1];
  o0 = o0 > 0.f ? o0 : (__expf(o0) - 1.f);
  o1 = o1 > 0.f ? o1 : (__expf(o1) - 1.f);
  unsigned int po = __builtin_bit_cast(unsigned int, __builtin_amdgcn_cvt_pkrtz(o0, o1));
  *(unsigned int*)(out + (long)wid * 128 + c0) = po;
}

// ---------------- per-dst aggregation, H=1, C=16, fp32 ----------------

__global__ void k_agg16(const float* __restrict__ h, const float* __restrict__ als,
                        const float* __restrict__ ald, const int* __restrict__ ptr,
                        const int* __restrict__ srcs, const float* __restrict__ bias,
                        float* __restrict__ out, int n, int lda) {
  int wid = (int)(((long)blockIdx.x * blockDim.x + threadIdx.x) >> 6);
  if (wid >= n) return;
  int lane = threadIdx.x & 63;
  int p0 = ptr[wid], deg = ptr[wid + 1] - p0;
  float aldv = ald[wid];
  float mx = -1e30f;
  for (int j = lane; j < deg; j += 64) {
    float l = als[srcs[p0 + j]] + aldv;
    l = l > 0.f ? l : 0.2f * l;
    mx = fmaxf(mx, l);
  }
  #pragma unroll
  for (int d = 1; d < 64; d <<= 1) mx = fmaxf(mx, __shfl_xor(mx, d));
  int g = lane >> 4, c = lane & 15;
  float acc = 0.f, dsum = 0.f;
  for (int j = g; j < deg; j += 4) {
    int s = srcs[p0 + j];
    float l = als[s] + aldv;
    l = l > 0.f ? l : 0.2f * l;
    float e = __expf(l - mx);
    dsum += e;
    acc += e * h[(long)s * lda + c];
  }
  #pragma unroll
  for (int d = 16; d < 64; d <<= 1) {
    acc += __shfl_xor(acc, d);
    dsum += __shfl_xor(dsum, d);
  }
  if (lane < 16)
    out[(long)wid * 16 + lane] = acc / (dsum + 1e-16f) + bias[lane];
}

// ---------------- launch ----------------

extern "C" void kernel_launch(void* const* d_in, const int* in_sizes, int n_in,
                              void* d_out, int out_size, void* d_ws, size_t ws_size,
                              hipStream_t stream) {
  const float* x  = (const float*)d_in[0];
  const int*   ei = (const int*)d_in[1];
  const float* W0 = (const float*)d_in[2];
  const float* as0= (const float*)d_in[3];
  const float* ad0= (const float*)d_in[4];
  const float* b0 = (const float*)d_in[5];
  const float* W1 = (const float*)d_in[6];
  const float* as1= (const float*)d_in[7];
  const float* ad1= (const float*)d_in[8];
  const float* b1 = (const float*)d_in[9];
  const float* W2 = (const float*)d_in[10];
  const float* as2= (const float*)d_in[11];
  const float* ad2= (const float*)d_in[12];
  const float* b2 = (const float*)d_in[13];
  float* out = (float*)d_out;

  int E = in_sizes[1] / 2;
  int n = in_sizes[0] / GENES;

  char* ws = (char*)d_ws;
  size_t off = 0;
  auto alloc = [&](size_t bytes) {
    void* p = ws + off;
    off = (off + bytes + 255) & ~(size_t)255;
    return p;
  };
  int* ptr   = (int*)alloc((size_t)(n + 1) * sizeof(int));
  int* cur   = (int*)alloc((size_t)n * sizeof(int));
  int* bsum  = (int*)alloc(512 * sizeof(int));
  int* srcs  = (int*)alloc((size_t)E * sizeof(int));
  unsigned short* Ah = (unsigned short*)alloc((size_t)n * 128 * sizeof(unsigned short));
  unsigned short* Bh = (unsigned short*)alloc((size_t)n * 128 * sizeof(unsigned short));
  float* A2  = (float*)alloc((size_t)n * 16 * sizeof(float));
  float* als = (float*)alloc((size_t)n * 8 * sizeof(float));
  float* ald = (float*)alloc((size_t)n * 8 * sizeof(float));
  unsigned short* P = (unsigned short*)alloc((size_t)163840 * sizeof(unsigned short));
  unsigned short* P0 = P;
  unsigned short* P1 = P + 131072;
  unsigned short* P2 = P + 147456;

  int eb = (E + 255) / 256;
  int nb = (n + 255) / 256;
  hipMemsetAsync(cur, 0, (size_t)n * sizeof(int), stream);
  k_deg<<<eb, 256, 0, stream>>>(ei, cur, E);
  k_scan1<<<nb, 256, 0, stream>>>(cur, ptr, bsum, n);
  k_scan2<<<1, 256, 0, stream>>>(bsum, nb);
  k_scan3<<<nb, 256, 0, stream>>>(ptr, bsum, n);
  hipMemsetAsync(cur, 0, (size_t)n * sizeof(int), stream);
  k_scatter<<<eb, 256, 0, stream>>>(ei, ptr, cur, srcs, E);
  k_wpackall<<<640, 256, 0, stream>>>(W0, W1, W2, P, GENES);

  int mgb  = (n + 63) / 64;
  int aggb = (int)(((long)n * 64 + 255) / 256);

  // layer 0: x @ W0 -> Ah fp16 (+als/ald), aggregate -> Bh fp16 (ELU)
  k_mgemm4<8, 8, false, true><<<mgb, 256, 0, stream>>>(
      x, P0, Ah, als, ald, as0, ad0, n, GENES, 32, 128);
  k_agg128h<<<aggb, 256, 0, stream>>>(Ah, als, ald, ptr, srcs, b0, Bh, n);

  // layer 1: Bh @ W1 -> Ah fp16 (+als/ald), aggregate -> Bh fp16 (ELU)
  k_mgemm4<8, 8, true, true><<<mgb, 256, 0, stream>>>(
      Bh, P1, Ah, als, ald, as1, ad1, n, 128, 4, 128);
  k_agg128h<<<aggb, 256, 0, stream>>>(Ah, als, ald, ptr, srcs, b1, Bh, n);

  // layer 2: Bh @ W2 (padded) -> A2 fp32 [n][16] (+als/ald H=1), aggregate -> out
  k_mgemm4<1, 1, true, false><<<mgb, 256, 0, stream>>>(
      Bh, P2, A2, als, ald, as2, ad2, n, 128, 4, 16);
  k_agg16<<<aggb, 256, 0, stream>>>(A2, als, ald, ptr, srcs, b2, out, n, 16);
}

// Round 8
// 423.449 us; speedup vs baseline: 1.0434x; 1.0428x over previous
//
#include <hip/hip_runtime.h>
#include <hip/hip_bf16.h>
#include <math.h>

#define GENES 1000

typedef __attribute__((ext_vector_type(8))) _Float16 half8;
typedef __attribute__((ext_vector_type(4))) float f32x4;
typedef __attribute__((ext_vector_type(4))) unsigned int uint4v;

// ---------------- CSR build ----------------

__global__ void k_deg(const int* __restrict__ ei, int* __restrict__ deg, int E) {
  int e = blockIdx.x * blockDim.x + threadIdx.x;
  if (e < E) atomicAdd(&deg[ei[E + e]], 1);
}

__global__ void k_scan1(const int* __restrict__ deg, int* __restrict__ ptr,
                        int* __restrict__ bsum, int n) {
  __shared__ int ws[4];
  int t = threadIdx.x, b = blockIdx.x;
  int i = b * 256 + t;
  int lane = t & 63, w = t >> 6;
  int x = (i < n) ? deg[i] : 0;
  #pragma unroll
  for (int d = 1; d < 64; d <<= 1) {
    int y = __shfl_up(x, d);
    if (lane >= d) x += y;
  }
  if (lane == 63) ws[w] = x;
  __syncthreads();
  if (t == 0) {
    int s = 0;
    #pragma unroll
    for (int k = 0; k < 4; ++k) { s += ws[k]; ws[k] = s; }
  }
  __syncthreads();
  int incl = x + (w ? ws[w - 1] : 0);
  if (i < n) ptr[i + 1] = incl;
  if (t == 255) bsum[b] = incl;
  if (i == 0) ptr[0] = 0;
}

__global__ void k_scan2(int* __restrict__ bsum, int nb) {
  __shared__ int ws[4];
  int t = threadIdx.x;
  int lane = t & 63, w = t >> 6;
  int v = (t < nb) ? bsum[t] : 0;
  int x = v;
  #pragma unroll
  for (int d = 1; d < 64; d <<= 1) {
    int y = __shfl_up(x, d);
    if (lane >= d) x += y;
  }
  if (lane == 63) ws[w] = x;
  __syncthreads();
  if (t == 0) {
    int s = 0;
    #pragma unroll
    for (int k = 0; k < 4; ++k) { s += ws[k]; ws[k] = s; }
  }
  __syncthreads();
  int incl = x + (w ? ws[w - 1] : 0);
  if (t < nb) bsum[t] = incl - v;
}

__global__ void k_scan3(int* __restrict__ ptr, const int* __restrict__ bsum, int n) {
  int i = blockIdx.x * 256 + threadIdx.x;
  if (i < n) ptr[i + 1] += bsum[blockIdx.x];
}

__global__ void k_scatter(const int* __restrict__ ei, const int* __restrict__ ptr,
                          int* __restrict__ cur, int* __restrict__ srcs, int E) {
  int e = blockIdx.x * blockDim.x + threadIdx.x;
  if (e >= E) return;
  int d = ei[E + e];
  int pos = ptr[d] + atomicAdd(&cur[d], 1);
  srcs[pos] = ei[e];
}

// ---------------- W pack (all 3 layers, one launch) ----------------
// element e = s*4096 + col*32 + kk (s = 32-wide k-step) -> fp16 at P[e].
// W0 -> 32 ksteps (K padded 1024), W1 -> 4, W2 -> 4 (cols padded to 128).

__global__ void k_wpackall(const float* __restrict__ W0, const float* __restrict__ W1,
                           const float* __restrict__ W2, unsigned short* __restrict__ P,
                           int K0) {
  int t = blockIdx.x * blockDim.x + threadIdx.x;  // 163840 total
  if (t >= 163840) return;
  const float* W; int K, N, e;
  if (t < 131072)      { W = W0; K = K0;  N = 128; e = t; }
  else if (t < 147456) { W = W1; K = 128; N = 128; e = t - 131072; }
  else                 { W = W2; K = 128; N = 16;  e = t - 147456; }
  int s = e >> 12, rem = e & 4095, col = rem >> 5, kk = rem & 31;
  int k = s * 32 + kk;
  float v = (k < K && col < N) ? W[(long)k * N + col] : 0.f;
  _Float16 h = (_Float16)v;
  P[t] = __builtin_bit_cast(unsigned short, h);
}

// ---------------- MFMA fp16 GEMM: B resident in LDS, barrier-free K loop -------
// 896 threads = 14 waves; wave wv owns rows blk*224 + wv*16 + r15, all NW*16 cols.
// NPH phases: fill NS ksteps (NS*8KB) of B into LDS, one barrier, then NS ksteps
// of MFMA with a 4-deep register ring for A (fully unrolled -> static indices).
// Fused epilogue: out (fp16 or fp32) + attention coefficients als/ald.

template<int HH, int NW, int NS, int NPH, bool AF16, bool OF16>
__global__ __launch_bounds__(896) void k_mgemm5(
    const void* __restrict__ Ap, const unsigned short* __restrict__ P,
    void* __restrict__ outp, float* __restrict__ als, float* __restrict__ ald,
    const float* __restrict__ avs, const float* __restrict__ avd,
    int M, int K, int ldc) {
  __shared__ unsigned short Bs[NS * 4096];
  int t = threadIdx.x, lane = t & 63, wv = t >> 6;
  int r15 = lane & 15, q = lane >> 4;
  long row = (long)blockIdx.x * 224 + wv * 16 + r15;
  bool rok = row < M;
  const float* a32 = (const float*)Ap + row * (long)K;
  const unsigned short* a16 = (const unsigned short*)Ap + row * (long)K;

  f32x4 acc[NW];
  #pragma unroll
  for (int nt = 0; nt < NW; ++nt) acc[nt] = (f32x4){0.f, 0.f, 0.f, 0.f};

  const uint4v z4 = (uint4v){0u, 0u, 0u, 0u};
  uint4v afa[4], afb[4];

  for (int ph = 0; ph < NPH; ++ph) {
    if (ph) __syncthreads();
    // ---- fill B phase (NS*512 16B units), linear copy ----
    {
      const uint4v* src = (const uint4v*)(P + (size_t)ph * NS * 4096);
      uint4v* dst = (uint4v*)&Bs[0];
      #pragma unroll 2
      for (int u = t; u < NS * 512; u += 896) dst[u] = src[u];
    }
    __syncthreads();

    // ---- A issue helper (j must be compile-time under unroll) ----
    auto issue = [&](int s, int j) {
      int k0 = (ph * NS + s) * 32 + q * 8;
      bool ok = rok && (k0 + 8 <= K);
      if constexpr (AF16) {
        afa[j] = ok ? *(const uint4v*)(a16 + k0) : z4;
      } else {
        afa[j] = ok ? *(const uint4v*)(a32 + k0) : z4;
        afb[j] = ok ? *(const uint4v*)(a32 + k0 + 4) : z4;
      }
    };

    #pragma unroll
    for (int j = 0; j < 4; ++j)
      if (j < NS) issue(j, j);

    #pragma unroll
    for (int s = 0; s < NS; ++s) {
      constexpr int JMASK = 3;
      int j = s & JMASK;
      half8 af;
      if constexpr (AF16) {
        af = __builtin_bit_cast(half8, afa[s & JMASK]);
      } else {
        float4 lo = __builtin_bit_cast(float4, afa[s & JMASK]);
        float4 hi = __builtin_bit_cast(float4, afb[s & JMASK]);
        uint4v au;
        au[0] = __builtin_bit_cast(unsigned int, __builtin_amdgcn_cvt_pkrtz(lo.x, lo.y));
        au[1] = __builtin_bit_cast(unsigned int, __builtin_amdgcn_cvt_pkrtz(lo.z, lo.w));
        au[2] = __builtin_bit_cast(unsigned int, __builtin_amdgcn_cvt_pkrtz(hi.x, hi.y));
        au[3] = __builtin_bit_cast(unsigned int, __builtin_amdgcn_cvt_pkrtz(hi.z, hi.w));
        af = __builtin_bit_cast(half8, au);
      }
      if (s + 4 < NS) issue(s + 4, j);
      #pragma unroll
      for (int nt = 0; nt < NW; ++nt) {
        const half8 bf = *(const half8*)((const char*)&Bs[0] +
                         s * 8192 + (nt * 16 + r15) * 64 + q * 16);
        acc[nt] = __builtin_amdgcn_mfma_f32_16x16x32_f16(af, bf, acc[nt], 0, 0, 0);
      }
    }
  }

  // ---- epilogue: C/D layout col=lane&15, row=(lane>>4)*4+i ----
  long rbase = (long)blockIdx.x * 224 + wv * 16 + q * 4;
  if constexpr (OF16) {
    unsigned short* o16 = (unsigned short*)outp;
    #pragma unroll
    for (int i = 0; i < 4; ++i) {
      long r = rbase + i;
      if (r < M) {
        #pragma unroll
        for (int nt = 0; nt < NW; ++nt) {
          _Float16 hv = (_Float16)acc[nt][i];
          o16[r * ldc + nt * 16 + r15] = __builtin_bit_cast(unsigned short, hv);
        }
      }
    }
  } else {
    float* o32 = (float*)outp;
    #pragma unroll
    for (int i = 0; i < 4; ++i) {
      long r = rbase + i;
      if (r < M) {
        #pragma unroll
        for (int nt = 0; nt < NW; ++nt)
          o32[r * ldc + nt * 16 + r15] = acc[nt][i];
      }
    }
  }
  // fused attention coefficients
  #pragma unroll
  for (int h = 0; h < HH; ++h) {
    float cs = avs[h * 16 + r15];
    float cd = avd[h * 16 + r15];
    #pragma unroll
    for (int i = 0; i < 4; ++i) {
      float s1 = acc[h][i] * cs;
      float s2 = acc[h][i] * cd;
      #pragma unroll
      for (int d = 1; d < 16; d <<= 1) {
        s1 += __shfl_xor(s1, d);
        s2 += __shfl_xor(s2, d);
      }
      if (r15 == 0) {
        long r = rbase + i;
        if (r < M) { als[r * HH + h] = s1; ald[r * HH + h] = s2; }
      }
    }
  }
}

// ---------------- per-dst aggregation, H=8, C=16, fp16 h in / fp16 out, ELU ----------------

__global__ void k_agg128h(const unsigned short* __restrict__ h,
                          const float* __restrict__ als, const float* __restrict__ ald,
                          const int* __restrict__ ptr, const int* __restrict__ srcs,
                          const float* __restrict__ bias,
                          unsigned short* __restrict__ out, int n) {
  int wid = (int)(((long)blockIdx.x * blockDim.x + threadIdx.x) >> 6);
  if (wid >= n) return;
  int lane = threadIdx.x & 63;
  int p0 = ptr[wid], deg = ptr[wid + 1] - p0;
  int hA = lane & 7;
  float aldA = ald[wid * 8 + hA];
  float mx = -1e30f;
  for (int j = (lane >> 3); j < deg; j += 8) {
    float l = als[srcs[p0 + j] * 8 + hA] + aldA;
    l = l > 0.f ? l : 0.2f * l;
    mx = fmaxf(mx, l);
  }
  #pragma unroll
  for (int d = 8; d < 64; d <<= 1) mx = fmaxf(mx, __shfl_xor(mx, d));
  int hB = lane >> 3;
  float m = __shfl(mx, hB);
  float aldB = ald[wid * 8 + hB];
  int c0 = 2 * lane;
  float acc0 = 0.f, acc1 = 0.f, dsum = 0.f;
  for (int j = 0; j < deg; ++j) {
    int s = srcs[p0 + j];
    float l = als[s * 8 + hB] + aldB;
    l = l > 0.f ? l : 0.2f * l;
    float e = __expf(l - m);
    dsum += e;
    unsigned int hv = *(const unsigned int*)(h + (long)s * 128 + c0);
    float f0 = (float)__builtin_bit_cast(_Float16, (unsigned short)(hv & 0xffffu));
    float f1 = (float)__builtin_bit_cast(_Float16, (unsigned short)(hv >> 16));
    acc0 += e * f0;
    acc1 += e * f1;
  }
  float inv = 1.f / (dsum + 1e-16f);
  float o0 = acc0 * inv + bias[c0];
  float o1 = acc1 * inv + bias[c0 + 1];
  o0 = o0 > 0.f ? o0 : (__expf(o0) - 1.f);
  o1 = o1 > 0.f ? o1 : (__expf(o1) - 1.f);
  unsigned int po = __builtin_bit_cast(unsigned int, __builtin_amdgcn_cvt_pkrtz(o0, o1));
  *(unsigned int*)(out + (long)wid * 128 + c0) = po;
}

// ---------------- per-dst aggregation, H=1, C=16, fp32 ----------------

__global__ void k_agg16(const float* __restrict__ h, const float* __restrict__ als,
                        const float* __restrict__ ald, const int* __restrict__ ptr,
                        const int* __restrict__ srcs, const float* __restrict__ bias,
                        float* __restrict__ out, int n, int lda) {
  int wid = (int)(((long)blockIdx.x * blockDim.x + threadIdx.x) >> 6);
  if (wid >= n) return;
  int lane = threadIdx.x & 63;
  int p0 = ptr[wid], deg = ptr[wid + 1] - p0;
  float aldv = ald[wid];
  float mx = -1e30f;
  for (int j = lane; j < deg; j += 64) {
    float l = als[srcs[p0 + j]] + aldv;
    l = l > 0.f ? l : 0.2f * l;
    mx = fmaxf(mx, l);
  }
  #pragma unroll
  for (int d = 1; d < 64; d <<= 1) mx = fmaxf(mx, __shfl_xor(mx, d));
  int g = lane >> 4, c = lane & 15;
  float acc = 0.f, dsum = 0.f;
  for (int j = g; j < deg; j += 4) {
    int s = srcs[p0 + j];
    float l = als[s] + aldv;
    l = l > 0.f ? l : 0.2f * l;
    float e = __expf(l - mx);
    dsum += e;
    acc += e * h[(long)s * lda + c];
  }
  #pragma unroll
  for (int d = 16; d < 64; d <<= 1) {
    acc += __shfl_xor(acc, d);
    dsum += __shfl_xor(dsum, d);
  }
  if (lane < 16)
    out[(long)wid * 16 + lane] = acc / (dsum + 1e-16f) + bias[lane];
}

// ---------------- launch ----------------

extern "C" void kernel_launch(void* const* d_in, const int* in_sizes, int n_in,
                              void* d_out, int out_size, void* d_ws, size_t ws_size,
                              hipStream_t stream) {
  const float* x  = (const float*)d_in[0];
  const int*   ei = (const int*)d_in[1];
  const float* W0 = (const float*)d_in[2];
  const float* as0= (const float*)d_in[3];
  const float* ad0= (const float*)d_in[4];
  const float* b0 = (const float*)d_in[5];
  const float* W1 = (const float*)d_in[6];
  const float* as1= (const float*)d_in[7];
  const float* ad1= (const float*)d_in[8];
  const float* b1 = (const float*)d_in[9];
  const float* W2 = (const float*)d_in[10];
  const float* as2= (const float*)d_in[11];
  const float* ad2= (const float*)d_in[12];
  const float* b2 = (const float*)d_in[13];
  float* out = (float*)d_out;

  int E = in_sizes[1] / 2;
  int n = in_sizes[0] / GENES;

  char* ws = (char*)d_ws;
  size_t off = 0;
  auto alloc = [&](size_t bytes) {
    void* p = ws + off;
    off = (off + bytes + 255) & ~(size_t)255;
    return p;
  };
  int* ptr   = (int*)alloc((size_t)(n + 1) * sizeof(int));
  int* cur   = (int*)alloc((size_t)n * sizeof(int));
  int* bsum  = (int*)alloc(512 * sizeof(int));
  int* srcs  = (int*)alloc((size_t)E * sizeof(int));
  unsigned short* Ah = (unsigned short*)alloc((size_t)n * 128 * sizeof(unsigned short));
  unsigned short* Bh = (unsigned short*)alloc((size_t)n * 128 * sizeof(unsigned short));
  float* A2  = (float*)alloc((size_t)n * 16 * sizeof(float));
  float* als = (float*)alloc((size_t)n * 8 * sizeof(float));
  float* ald = (float*)alloc((size_t)n * 8 * sizeof(float));
  unsigned short* P = (unsigned short*)alloc((size_t)163840 * sizeof(unsigned short));
  unsigned short* P0 = P;
  unsigned short* P1 = P + 131072;
  unsigned short* P2 = P + 147456;

  int eb = (E + 255) / 256;
  int nb = (n + 255) / 256;
  hipMemsetAsync(cur, 0, (size_t)n * sizeof(int), stream);
  k_deg<<<eb, 256, 0, stream>>>(ei, cur, E);
  k_scan1<<<nb, 256, 0, stream>>>(cur, ptr, bsum, n);
  k_scan2<<<1, 256, 0, stream>>>(bsum, nb);
  k_scan3<<<nb, 256, 0, stream>>>(ptr, bsum, n);
  hipMemsetAsync(cur, 0, (size_t)n * sizeof(int), stream);
  k_scatter<<<eb, 256, 0, stream>>>(ei, ptr, cur, srcs, E);
  k_wpackall<<<640, 256, 0, stream>>>(W0, W1, W2, P, GENES);

  int mgb  = (n + 223) / 224;
  int aggb = (int)(((long)n * 64 + 255) / 256);

  // layer 0: x @ W0 -> Ah fp16 (+als/ald), aggregate -> Bh fp16 (ELU)
  k_mgemm5<8, 8, 16, 2, false, true><<<mgb, 896, 0, stream>>>(
      x, P0, Ah, als, ald, as0, ad0, n, GENES, 128);
  k_agg128h<<<aggb, 256, 0, stream>>>(Ah, als, ald, ptr, srcs, b0, Bh, n);

  // layer 1: Bh @ W1 -> Ah fp16 (+als/ald), aggregate -> Bh fp16 (ELU)
  k_mgemm5<8, 8, 4, 1, true, true><<<mgb, 896, 0, stream>>>(
      Bh, P1, Ah, als, ald, as1, ad1, n, 128, 128);
  k_agg128h<<<aggb, 256, 0, stream>>>(Ah, als, ald, ptr, srcs, b1, Bh, n);

  // layer 2: Bh @ W2 (padded) -> A2 fp32 [n][16] (+als/ald H=1), aggregate -> out
  k_mgemm5<1, 1, 4, 1, true, false><<<mgb, 896, 0, stream>>>(
      Bh, P2, A2, als, ald, as2, ad2, n, 128, 16);
  k_agg16<<<aggb, 256, 0, stream>>>(A2, als, ald, ptr, srcs, b2, out, n, 16);
}